// Round 1
// baseline (289.138 us; speedup 1.0000x reference)
//
#include <hip/hip_runtime.h>

// Problem constants: B=1024, S=512, M=64, K=64, V=128, E=64, NQ=10000, C=4.

// Workspace layout (float offsets)
#define WS_QSIM   0          // [10001][64]
#define WS_BIAS   640064     // [512][64]
#define WS_GT     672832     // [64][512]  g transposed
#define WS_GZT    705600     // [64][512]  g*z transposed
#define WS_TP     738368     // [512][64]  tp_{t-1}
#define WS_CONST  771136     // du, dw, dc, sp
#define WS_P0     771152     // [64]
#define WS_Z0     771216     // [64]
// total 771280 floats = 3.09 MB

__device__ __forceinline__ float wred_sum(float x) {
    x += __shfl_xor(x, 1);
    x += __shfl_xor(x, 2);
    x += __shfl_xor(x, 4);
    x += __shfl_xor(x, 8);
    x += __shfl_xor(x, 16);
    x += __shfl_xor(x, 32);
    return x;
}

__device__ __forceinline__ float softplusf(float x) {
    // jax.nn.softplus = logaddexp(x, 0)
    return fmaxf(x, 0.0f) + log1pf(__expf(-fabsf(x)));
}

// ---------------------------------------------------------------------------
// k_prep: blocks [0,626): qsim[q,m] = (q_table[q]@q2k_w + q2k_b) . key_embeds[m]
//         blocks [626,658): bias[s,m] = 0.3*alpha + 0.2*diff_sim
//         block 658: scalar constants + P0/Z0
// ---------------------------------------------------------------------------
__global__ __launch_bounds__(256) void k_prep(
    const float* __restrict__ q_table, const float* __restrict__ key_embeds,
    const float* __restrict__ q2k_w, const float* __restrict__ q2k_b,
    const float* __restrict__ alpha_mean, const float* __restrict__ alpha_log_var,
    const float* __restrict__ beta_base, const float* __restrict__ beta_offsets,
    const float* __restrict__ alpha_noise, const float* __restrict__ beta_noise,
    const float* __restrict__ qa_w, const float* __restrict__ qa_b,
    const float* __restrict__ qae_w, const float* __restrict__ qae_b,
    const float* __restrict__ pred_w,
    const float* __restrict__ th0, const float* __restrict__ lv0,
    float* __restrict__ ws)
{
    const int tid = threadIdx.x;
    const int bid = blockIdx.x;
    if (bid < 626) {
        __shared__ float sw[64 * 64];    // q2k_w [e][k]
        __shared__ float ske[64 * 65];   // key_embeds [m][k], padded (+1) stride
        for (int i = tid; i < 4096; i += 256) sw[i] = q2k_w[i];
        for (int i = tid; i < 4096; i += 256) ske[(i >> 6) * 65 + (i & 63)] = key_embeds[i];
        __syncthreads();
        const int wid = tid >> 6, lane = tid & 63;
        float* qsim = ws + WS_QSIM;
        for (int qq = 0; qq < 4; ++qq) {
            int q = bid * 16 + wid * 4 + qq;
            int qc = (q < 10001) ? q : 10000;
            float qe = q_table[qc * 64 + lane];      // lane = e
            float qk = q2k_b[lane];                  // lane = k
            #pragma unroll
            for (int e = 0; e < 64; ++e)
                qk = fmaf(__shfl(qe, e), sw[e * 64 + lane], qk);
            float sim = 0.0f;                        // lane = m
            #pragma unroll
            for (int k = 0; k < 64; ++k)
                sim = fmaf(__shfl(qk, k), ske[lane * 65 + k], sim);
            if (q < 10001) qsim[q * 64 + lane] = sim;
        }
    } else if (bid < 658) {
        float* bias = ws + WS_BIAS;
        int base = (bid - 626) * 1024 + tid * 4;
        #pragma unroll
        for (int j = 0; j < 4; ++j) {
            int idx = base + j;
            int m = idx & 63;
            float sdev  = __expf(0.5f * alpha_log_var[m]);
            float alpha = __expf(fmaf(alpha_noise[idx], sdev, alpha_mean[m]));
            float bse   = fmaf(beta_noise[idx], 0.1f, beta_base[m]);
            float o0 = softplusf(beta_offsets[m * 3 + 0]);
            float o1 = softplusf(beta_offsets[m * 3 + 1]);
            float cmean = (o0 + (o0 + o1)) * (1.0f / 3.0f);  // mean of {0, o0, o0+o1}
            float bm = bse + cmean;
            float diff = __expf(-0.5f * bm * bm);
            bias[idx] = fmaf(0.3f, alpha, 0.2f * diff);
        }
    } else {
        const int wid = tid >> 6, lane = tid & 63;
        if (wid == 0) {
            // qv[e] = qae_w[e,:] @ pred_w
            float qv = 0.0f;
            for (int v = 0; v < 128; ++v) qv = fmaf(qae_w[lane * 128 + v], pred_w[v], qv);
            float du  = wred_sum(qa_w[lane] * qv);
            float dw  = wred_sum(qa_w[64 + lane] * qv);
            float dc1 = wred_sum(qa_b[lane] * qv);
            float cb  = wred_sum(fmaf(qae_b[lane], pred_w[lane],
                                      qae_b[64 + lane] * pred_w[64 + lane]));
            float sp  = wred_sum(pred_w[lane] + pred_w[64 + lane]);
            if (lane == 0) {
                float* c = ws + WS_CONST;
                c[0] = du; c[1] = dw; c[2] = dc1 + cb; c[3] = sp;
            }
        } else if (wid == 1) {
            float z0 = 0.0f;   // lane = m
            for (int v = 0; v < 128; ++v) z0 = fmaf(th0[lane * 128 + v], pred_w[v], z0);
            ws[WS_Z0 + lane] = z0;
            ws[WS_P0 + lane] = __expf(-lv0[lane * 128]);
        }
    }
}

// ---------------------------------------------------------------------------
// k_reduce: one block per t. lane = m. For each b: softmax row, accumulate
//   A1 = sum_b a, A2 = sum_b a*pr, A3 = sum_b a^2*y.  Then g, g*z per (t,m).
// ---------------------------------------------------------------------------
__global__ __launch_bounds__(512) void k_reduce(
    const int* __restrict__ q_ids, const int* __restrict__ responses,
    float* __restrict__ ws)
{
    const int t = blockIdx.x;
    const int wid = threadIdx.x >> 6, lane = threadIdx.x & 63;
    const float* qsim = ws + WS_QSIM;
    const float* cst  = ws + WS_CONST;
    const float du = cst[0], dw = cst[1], dc = cst[2], sp = cst[3];
    const float biasv = ws[WS_BIAS + t * 64 + lane];

    // response LUT (4 values): ability_ev
    float ae0, ae1, ae2, ae3;
    {
        float p;
        p = 0.01f;        ae0 = logf(p) - log1pf(-p);
        p = 0.33333334f;  ae1 = logf(p) - log1pf(-p);
        p = 0.6666667f;   ae2 = logf(p) - log1pf(-p);
        p = 0.99f;        ae3 = logf(p) - log1pf(-p);
    }

    float a1 = 0.0f, a2 = 0.0f, a3 = 0.0f;
    #pragma unroll 4
    for (int i = 0; i < 128; ++i) {
        int b = (i << 3) | wid;
        int off = __builtin_amdgcn_readfirstlane(b * 512 + t);
        int qid = q_ids[off];
        int resp = responses[off];
        float e = __expf(qsim[qid * 64 + lane] + biasv);
        float s = wred_sum(e);
        float a = e * __builtin_amdgcn_rcpf(s);
        float rn = (float)resp * 0.33333334f;
        float ae = (resp == 0) ? ae0 : (resp == 1) ? ae1 : (resp == 2) ? ae2 : ae3;
        float pr = fmaf(fabsf(rn - 0.5f), 2.0f, 0.5f);
        float x1 = (float)qid * 1e-4f;
        float y = fmaf(ae, sp, fmaf(rn, dw, fmaf(x1, du, dc)));
        a1 += a;
        a2 = fmaf(a, pr, a2);
        a3 = fmaf(a * a, y, a3);
    }

    __shared__ float red[24 * 64];
    red[(wid * 3 + 0) * 64 + lane] = a1;
    red[(wid * 3 + 1) * 64 + lane] = a2;
    red[(wid * 3 + 2) * 64 + lane] = a3;
    __syncthreads();
    if (wid == 0) {
        float A1 = 0.0f, A2 = 0.0f, A3 = 0.0f;
        #pragma unroll
        for (int w = 0; w < 8; ++w) {
            A1 += red[(w * 3 + 0) * 64 + lane];
            A2 += red[(w * 3 + 1) * 64 + lane];
            A3 += red[(w * 3 + 2) * 64 + lane];
        }
        float denom = A1 + 1e-8f;
        float g = (A2 / denom) * (A1 * (1.0f / 1024.0f));  // agg_pr * w
        float z = 0.5f * (A3 / denom);
        ws[WS_GT  + lane * 512 + t] = g;
        ws[WS_GZT + lane * 512 + t] = g * z;
    }
}

// ---------------------------------------------------------------------------
// k_scan: one block (1 wave) per m. Exclusive prefix scan over t of (g, g*z);
//   tp[t,m] = (Z0 + sum_{tau<t} g*z) / (P0 + sum_{tau<t} g)
// ---------------------------------------------------------------------------
__global__ __launch_bounds__(64) void k_scan(float* __restrict__ ws)
{
    const int m = blockIdx.x, lane = threadIdx.x;
    const float* gT  = ws + WS_GT  + m * 512;
    const float* gzT = ws + WS_GZT + m * 512;
    float g[8], gz[8];
    #pragma unroll
    for (int j = 0; j < 8; ++j) { g[j] = gT[lane * 8 + j]; gz[j] = gzT[lane * 8 + j]; }
    float sg = 0.0f, sz = 0.0f;
    #pragma unroll
    for (int j = 0; j < 8; ++j) { sg += g[j]; sz += gz[j]; }
    #pragma unroll
    for (int d = 1; d < 64; d <<= 1) {
        float t1 = __shfl_up(sg, d);
        float t2 = __shfl_up(sz, d);
        if (lane >= d) { sg += t1; sz += t2; }
    }
    float eg = __shfl_up(sg, 1);
    float ez = __shfl_up(sz, 1);
    if (lane == 0) { eg = 0.0f; ez = 0.0f; }
    float P = ws[WS_P0 + m] + eg;
    float Z = ws[WS_Z0 + m] + ez;
    float* tp = ws + WS_TP;
    #pragma unroll
    for (int j = 0; j < 8; ++j) {
        int t = lane * 8 + j;
        tp[t * 64 + m] = Z / P;
        Z += gz[j];
        P += g[j];
    }
}

// ---------------------------------------------------------------------------
// k_pred: one block per b, lane = m. pred[b,t] = (sum_m e*tp) / (sum_m e) + pb
// ---------------------------------------------------------------------------
__global__ __launch_bounds__(512) void k_pred(
    const int* __restrict__ q_ids, const float* __restrict__ pred_b,
    const float* __restrict__ ws, float* __restrict__ out)
{
    const int b = blockIdx.x;
    const int wid = threadIdx.x >> 6, lane = threadIdx.x & 63;
    const float* qsim = ws + WS_QSIM;
    const float* bias = ws + WS_BIAS;
    const float* tp   = ws + WS_TP;
    const float pb = pred_b[0];
    const int t0 = wid * 64;
    float keep = 0.0f;
    #pragma unroll 2
    for (int i = 0; i < 64; ++i) {
        int t = t0 + i;
        int qid = q_ids[__builtin_amdgcn_readfirstlane(b * 512 + t)];
        float e = __expf(qsim[qid * 64 + lane] + bias[t * 64 + lane]);
        float num = e * tp[t * 64 + lane];
        float den = wred_sum(e);
        num = wred_sum(num);
        float predv = fmaf(num, __builtin_amdgcn_rcpf(den), pb);
        if (lane == i) keep = predv;
    }
    out[b * 512 + t0 + lane] = keep;
}

// ---------------------------------------------------------------------------
extern "C" void kernel_launch(void* const* d_in, const int* in_sizes, int n_in,
                              void* d_out, int out_size, void* d_ws, size_t ws_size,
                              hipStream_t stream)
{
    (void)in_sizes; (void)n_in; (void)out_size; (void)ws_size;
    const int*   q_ids         = (const int*)d_in[0];
    const int*   responses     = (const int*)d_in[1];
    const float* q_table       = (const float*)d_in[2];
    const float* key_embeds    = (const float*)d_in[3];
    const float* alpha_mean    = (const float*)d_in[4];
    const float* alpha_log_var = (const float*)d_in[5];
    const float* beta_base     = (const float*)d_in[6];
    const float* beta_offsets  = (const float*)d_in[7];
    const float* th0           = (const float*)d_in[8];
    const float* lv0           = (const float*)d_in[9];
    const float* q2k_w         = (const float*)d_in[10];
    const float* q2k_b         = (const float*)d_in[11];
    const float* qa_w          = (const float*)d_in[12];
    const float* qa_b          = (const float*)d_in[13];
    const float* qae_w         = (const float*)d_in[14];
    const float* qae_b         = (const float*)d_in[15];
    const float* pred_w        = (const float*)d_in[16];
    const float* pred_bs       = (const float*)d_in[17];
    const float* alpha_noise   = (const float*)d_in[18];
    const float* beta_noise    = (const float*)d_in[19];
    float* ws  = (float*)d_ws;
    float* out = (float*)d_out;

    k_prep<<<dim3(659), dim3(256), 0, stream>>>(
        q_table, key_embeds, q2k_w, q2k_b, alpha_mean, alpha_log_var,
        beta_base, beta_offsets, alpha_noise, beta_noise,
        qa_w, qa_b, qae_w, qae_b, pred_w, th0, lv0, ws);
    k_reduce<<<dim3(512), dim3(512), 0, stream>>>(q_ids, responses, ws);
    k_scan<<<dim3(64), dim3(64), 0, stream>>>(ws);
    k_pred<<<dim3(1024), dim3(512), 0, stream>>>(q_ids, pred_bs, ws, out);
}

// Round 2
// 164.731 us; speedup vs baseline: 1.7552x; 1.7552x over previous
//
#include <hip/hip_runtime.h>

// B=1024, S=512, M=64, K=64, V=128, E=64, NQ=10000, C=4.

// Workspace layout (float offsets)
#define WS_EQ     0          // eq[10001][64]  = exp(qsim)
#define WS_EB     640064     // eb[512][64]    = exp(bias)
#define WS_PACK   672832     // int packT[512][1024] = qid | resp<<16
#define WS_PAT    1197120    // partials [3][2][64][512]  (i, half, m, t)
#define WS_W1     1393728    // w1[512][64] = eb * tp
#define WS_CONST  1426496    // du, dw, dc, sp
#define WS_P0     1426512    // [64]
#define WS_Z0     1426576    // [64]
// total 1426640 floats = 5.71 MB

__device__ __forceinline__ float wred_sum(float x) {
    x += __shfl_xor(x, 1);
    x += __shfl_xor(x, 2);
    x += __shfl_xor(x, 4);
    x += __shfl_xor(x, 8);
    x += __shfl_xor(x, 16);
    x += __shfl_xor(x, 32);
    return x;
}

__device__ __forceinline__ float softplusf(float x) {
    return fmaxf(x, 0.0f) + log1pf(__expf(-fabsf(x)));
}

// ---------------------------------------------------------------------------
// k_prep:
//   blocks [0,626):   eq[q,m] = exp((q_table[q]@q2k_w + q2k_b) . key_embeds[m])
//   blocks [626,658): eb[t,m] = exp(0.3*alpha + 0.2*diff_sim)
//   block 658:        scalar constants + P0/Z0
//   blocks [659,787): tile-transpose q_ids/responses -> packT[s][b]
// ---------------------------------------------------------------------------
__global__ __launch_bounds__(256) void k_prep(
    const int* __restrict__ q_ids, const int* __restrict__ responses,
    const float* __restrict__ q_table, const float* __restrict__ key_embeds,
    const float* __restrict__ q2k_w, const float* __restrict__ q2k_b,
    const float* __restrict__ alpha_mean, const float* __restrict__ alpha_log_var,
    const float* __restrict__ beta_base, const float* __restrict__ beta_offsets,
    const float* __restrict__ alpha_noise, const float* __restrict__ beta_noise,
    const float* __restrict__ qa_w, const float* __restrict__ qa_b,
    const float* __restrict__ qae_w, const float* __restrict__ qae_b,
    const float* __restrict__ pred_w,
    const float* __restrict__ th0, const float* __restrict__ lv0,
    float* __restrict__ ws)
{
    const int tid = threadIdx.x;
    const int bid = blockIdx.x;
    if (bid < 626) {
        __shared__ float sw[64 * 64];    // q2k_w [e][k]
        __shared__ float ske[64 * 65];   // key_embeds [m][k], padded stride
        for (int i = tid; i < 4096; i += 256) sw[i] = q2k_w[i];
        for (int i = tid; i < 4096; i += 256) ske[(i >> 6) * 65 + (i & 63)] = key_embeds[i];
        __syncthreads();
        const int wid = tid >> 6, lane = tid & 63;
        float* eq = ws + WS_EQ;
        for (int qq = 0; qq < 4; ++qq) {
            int q = bid * 16 + wid * 4 + qq;
            int qc = (q < 10001) ? q : 10000;
            float qe = q_table[qc * 64 + lane];      // lane = e
            float qk = q2k_b[lane];                  // lane = k
            #pragma unroll
            for (int e = 0; e < 64; ++e)
                qk = fmaf(__shfl(qe, e), sw[e * 64 + lane], qk);
            float sim = 0.0f;                        // lane = m
            #pragma unroll
            for (int k = 0; k < 64; ++k)
                sim = fmaf(__shfl(qk, k), ske[lane * 65 + k], sim);
            if (q < 10001) eq[q * 64 + lane] = __expf(sim);
        }
    } else if (bid < 658) {
        float* eb = ws + WS_EB;
        int base = (bid - 626) * 1024 + tid * 4;
        #pragma unroll
        for (int j = 0; j < 4; ++j) {
            int idx = base + j;
            int m = idx & 63;
            float sdev  = __expf(0.5f * alpha_log_var[m]);
            float alpha = __expf(fmaf(alpha_noise[idx], sdev, alpha_mean[m]));
            float bse   = fmaf(beta_noise[idx], 0.1f, beta_base[m]);
            float o0 = softplusf(beta_offsets[m * 3 + 0]);
            float o1 = softplusf(beta_offsets[m * 3 + 1]);
            float cmean = (o0 + (o0 + o1)) * (1.0f / 3.0f);
            float bm = bse + cmean;
            float diff = __expf(-0.5f * bm * bm);
            eb[idx] = __expf(fmaf(0.3f, alpha, 0.2f * diff));
        }
    } else if (bid == 658) {
        const int wid = tid >> 6, lane = tid & 63;
        if (wid == 0) {
            float qv = 0.0f;
            for (int v = 0; v < 128; ++v) qv = fmaf(qae_w[lane * 128 + v], pred_w[v], qv);
            float du  = wred_sum(qa_w[lane] * qv);
            float dw  = wred_sum(qa_w[64 + lane] * qv);
            float dc1 = wred_sum(qa_b[lane] * qv);
            float cb  = wred_sum(fmaf(qae_b[lane], pred_w[lane],
                                      qae_b[64 + lane] * pred_w[64 + lane]));
            float sp  = wred_sum(pred_w[lane] + pred_w[64 + lane]);
            if (lane == 0) {
                float* c = ws + WS_CONST;
                c[0] = du; c[1] = dw; c[2] = dc1 + cb; c[3] = sp;
            }
        } else if (wid == 1) {
            float z0 = 0.0f;   // lane = m
            for (int v = 0; v < 128; ++v) z0 = fmaf(th0[lane * 128 + v], pred_w[v], z0);
            ws[WS_Z0 + lane] = z0;
            ws[WS_P0 + lane] = __expf(-lv0[lane * 128]);
        }
    } else {
        // transpose + pack: packT[s][b] = qid | resp<<16
        int tb = bid - 659;            // 0..127
        int sb = tb & 7;               // s-tile (8)
        int bb = tb >> 3;              // b-tile (16)
        __shared__ int tile[64][65];
        #pragma unroll
        for (int j = 0; j < 16; ++j) {
            int row = (tid >> 6) * 16 + j;   // b-dim within tile
            int col = tid & 63;              // s-dim within tile
            int gi = (bb * 64 + row) * 512 + sb * 64 + col;
            tile[row][col] = q_ids[gi] | (responses[gi] << 16);
        }
        __syncthreads();
        int* packT = (int*)(ws + WS_PACK);
        #pragma unroll
        for (int j = 0; j < 16; ++j) {
            int row = (tid >> 6) * 16 + j;   // s-dim
            int col = tid & 63;              // b-dim
            packT[(sb * 64 + row) * 1024 + bb * 64 + col] = tile[col][row];
        }
    }
}

// ---------------------------------------------------------------------------
// k_reduce: grid (t, half). Wave lane layout (r,c)=4 rows x 16 lanes, float4
// per lane. Per iteration: 4 softmax rows, accumulate A1=sum a, A2=sum a*pr,
// A3=sum a^2*y. Partials written to PAT[i][h][m][t].
// ---------------------------------------------------------------------------
__global__ __launch_bounds__(512) void k_reduce(float* __restrict__ ws)
{
    const int bid = blockIdx.x;
    const int t = bid & 511, h = bid >> 9;
    const int tid = threadIdx.x;
    const int wid = tid >> 6, lane = tid & 63;
    const int r = lane >> 4, c = lane & 15;
    const float* eq = ws + WS_EQ;
    const int* packT = (const int*)(ws + WS_PACK);
    const float* cst = ws + WS_CONST;
    const float du = cst[0], dw = cst[1], dc = cst[2], sp = cst[3];

    float ae0, ae1, ae2, ae3;
    {
        float p;
        p = 0.01f;        ae0 = logf(p) - log1pf(-p);
        p = 0.33333334f;  ae1 = logf(p) - log1pf(-p);
        p = 0.6666667f;   ae2 = logf(p) - log1pf(-p);
        p = 0.99f;        ae3 = logf(p) - log1pf(-p);
    }

    // preload this wave's 64 b's
    int pk = packT[t * 1024 + h * 512 + wid * 64 + lane];
    int qid_l = pk & 0xFFFF;
    int resp  = pk >> 16;
    float rn  = (float)resp * 0.33333334f;
    float ae  = (resp == 0) ? ae0 : (resp == 1) ? ae1 : (resp == 2) ? ae2 : ae3;
    float pr_l = fmaf(fabsf(rn - 0.5f), 2.0f, 0.5f);
    float y_l  = fmaf(ae, sp, fmaf(rn, dw, fmaf((float)qid_l * 1e-4f, du, dc)));

    const float4 ebv = *(const float4*)(ws + WS_EB + t * 64 + c * 4);

    float4 a1v = {0.f,0.f,0.f,0.f}, a2v = {0.f,0.f,0.f,0.f}, a3v = {0.f,0.f,0.f,0.f};
    #pragma unroll 4
    for (int i = 0; i < 16; ++i) {
        int src = i * 4 + r;
        int qid  = __shfl(qid_l, src);
        float yv = __shfl(y_l, src);
        float pv = __shfl(pr_l, src);
        float4 eqv = *(const float4*)(eq + qid * 64 + c * 4);
        float4 e4;
        e4.x = eqv.x * ebv.x; e4.y = eqv.y * ebv.y;
        e4.z = eqv.z * ebv.z; e4.w = eqv.w * ebv.w;
        float s = (e4.x + e4.y) + (e4.z + e4.w);
        s += __shfl_xor(s, 1);
        s += __shfl_xor(s, 2);
        s += __shfl_xor(s, 4);
        s += __shfl_xor(s, 8);
        float rinv = __builtin_amdgcn_rcpf(s);
        float4 a4;
        a4.x = e4.x * rinv; a4.y = e4.y * rinv; a4.z = e4.z * rinv; a4.w = e4.w * rinv;
        a1v.x += a4.x; a1v.y += a4.y; a1v.z += a4.z; a1v.w += a4.w;
        a2v.x = fmaf(a4.x, pv, a2v.x); a2v.y = fmaf(a4.y, pv, a2v.y);
        a2v.z = fmaf(a4.z, pv, a2v.z); a2v.w = fmaf(a4.w, pv, a2v.w);
        a3v.x = fmaf(a4.x * a4.x, yv, a3v.x); a3v.y = fmaf(a4.y * a4.y, yv, a3v.y);
        a3v.z = fmaf(a4.z * a4.z, yv, a3v.z); a3v.w = fmaf(a4.w * a4.w, yv, a3v.w);
    }
    // combine the 4 r-groups (different b's, same m-range)
    #pragma unroll
    for (int d = 16; d <= 32; d <<= 1) {
        a1v.x += __shfl_xor(a1v.x, d); a1v.y += __shfl_xor(a1v.y, d);
        a1v.z += __shfl_xor(a1v.z, d); a1v.w += __shfl_xor(a1v.w, d);
        a2v.x += __shfl_xor(a2v.x, d); a2v.y += __shfl_xor(a2v.y, d);
        a2v.z += __shfl_xor(a2v.z, d); a2v.w += __shfl_xor(a2v.w, d);
        a3v.x += __shfl_xor(a3v.x, d); a3v.y += __shfl_xor(a3v.y, d);
        a3v.z += __shfl_xor(a3v.z, d); a3v.w += __shfl_xor(a3v.w, d);
    }

    __shared__ float red[8][3][64];
    if (lane < 16) {
        *(float4*)&red[wid][0][lane * 4] = a1v;
        *(float4*)&red[wid][1][lane * 4] = a2v;
        *(float4*)&red[wid][2][lane * 4] = a3v;
    }
    __syncthreads();
    if (wid == 0) {
        float A1 = 0.f, A2 = 0.f, A3 = 0.f;
        #pragma unroll
        for (int w = 0; w < 8; ++w) {
            A1 += red[w][0][lane]; A2 += red[w][1][lane]; A3 += red[w][2][lane];
        }
        float* pat = ws + WS_PAT;
        pat[(h * 64 + lane) * 512 + t]           = A1;
        pat[65536 + (h * 64 + lane) * 512 + t]   = A2;
        pat[131072 + (h * 64 + lane) * 512 + t]  = A3;
    }
}

// ---------------------------------------------------------------------------
// k_scan: block per m, 1 wave. Combine halves, form g/gz, exclusive prefix
// scan over t, write w1[t,m] = eb[t,m] * (Z_{t-1}/P_{t-1}).
// ---------------------------------------------------------------------------
__global__ __launch_bounds__(64) void k_scan(float* __restrict__ ws)
{
    const int m = blockIdx.x, lane = threadIdx.x;
    const float* pat = ws + WS_PAT;
    float A1[8], A2[8], A3[8];
    #pragma unroll
    for (int i = 0; i < 3; ++i) {
        const float* p0 = pat + i * 65536 + m * 512 + lane * 8;
        const float* p1 = p0 + 32768;
        float4 u0 = *(const float4*)p0, u1 = *(const float4*)(p0 + 4);
        float4 v0 = *(const float4*)p1, v1 = *(const float4*)(p1 + 4);
        float* A = (i == 0) ? A1 : (i == 1) ? A2 : A3;
        A[0] = u0.x + v0.x; A[1] = u0.y + v0.y; A[2] = u0.z + v0.z; A[3] = u0.w + v0.w;
        A[4] = u1.x + v1.x; A[5] = u1.y + v1.y; A[6] = u1.z + v1.z; A[7] = u1.w + v1.w;
    }
    float g[8], gz[8];
    #pragma unroll
    for (int j = 0; j < 8; ++j) {
        float denom = A1[j] + 1e-8f;
        float gg = (A2[j] / denom) * (A1[j] * (1.0f / 1024.0f));
        float zz = 0.5f * (A3[j] / denom);
        g[j] = gg; gz[j] = gg * zz;
    }
    float sg = 0.0f, sz = 0.0f;
    #pragma unroll
    for (int j = 0; j < 8; ++j) { sg += g[j]; sz += gz[j]; }
    #pragma unroll
    for (int d = 1; d < 64; d <<= 1) {
        float t1 = __shfl_up(sg, d);
        float t2 = __shfl_up(sz, d);
        if (lane >= d) { sg += t1; sz += t2; }
    }
    float eg = __shfl_up(sg, 1);
    float ez = __shfl_up(sz, 1);
    if (lane == 0) { eg = 0.0f; ez = 0.0f; }
    float P = ws[WS_P0 + m] + eg;
    float Z = ws[WS_Z0 + m] + ez;
    const float* eb = ws + WS_EB;
    float* w1 = ws + WS_W1;
    #pragma unroll
    for (int j = 0; j < 8; ++j) {
        int t = lane * 8 + j;
        w1[t * 64 + m] = (Z / P) * eb[t * 64 + m];
        Z += gz[j];
        P += g[j];
    }
}

// ---------------------------------------------------------------------------
// k_pred: block per b, wave lane layout (r,c). pred[b,t] =
//   (sum_m eq*w1) / (sum_m eq*eb) + pb.  4 t's per iteration.
// ---------------------------------------------------------------------------
__global__ __launch_bounds__(512) void k_pred(
    const int* __restrict__ q_ids, const float* __restrict__ pred_b,
    const float* __restrict__ ws, float* __restrict__ out)
{
    const int b = blockIdx.x;
    const int tid = threadIdx.x, wid = tid >> 6, lane = tid & 63;
    const int r = lane >> 4, c = lane & 15;
    const int t0 = wid * 64;
    const float* eq = ws + WS_EQ;
    const float* eb = ws + WS_EB;
    const float* w1 = ws + WS_W1;
    const float pb = pred_b[0];
    int qid_l = q_ids[b * 512 + t0 + lane];
    float keep = 0.0f;
    #pragma unroll 4
    for (int i = 0; i < 16; ++i) {
        int src = i * 4 + r;
        int qid = __shfl(qid_l, src);
        int t = t0 + i * 4 + r;
        float4 eqv = *(const float4*)(eq + qid * 64 + c * 4);
        float4 ebv = *(const float4*)(eb + t * 64 + c * 4);
        float4 w1v = *(const float4*)(w1 + t * 64 + c * 4);
        float den = fmaf(eqv.w, ebv.w, fmaf(eqv.z, ebv.z, fmaf(eqv.y, ebv.y, eqv.x * ebv.x)));
        float num = fmaf(eqv.w, w1v.w, fmaf(eqv.z, w1v.z, fmaf(eqv.y, w1v.y, eqv.x * w1v.x)));
        den += __shfl_xor(den, 1); num += __shfl_xor(num, 1);
        den += __shfl_xor(den, 2); num += __shfl_xor(num, 2);
        den += __shfl_xor(den, 4); num += __shfl_xor(num, 4);
        den += __shfl_xor(den, 8); num += __shfl_xor(num, 8);
        float predv = fmaf(num, __builtin_amdgcn_rcpf(den), pb);
        float v = __shfl(predv, (lane & 3) * 16);
        if ((lane >> 2) == i) keep = v;
    }
    out[b * 512 + t0 + lane] = keep;
}

// ---------------------------------------------------------------------------
extern "C" void kernel_launch(void* const* d_in, const int* in_sizes, int n_in,
                              void* d_out, int out_size, void* d_ws, size_t ws_size,
                              hipStream_t stream)
{
    (void)in_sizes; (void)n_in; (void)out_size; (void)ws_size;
    const int*   q_ids         = (const int*)d_in[0];
    const int*   responses     = (const int*)d_in[1];
    const float* q_table       = (const float*)d_in[2];
    const float* key_embeds    = (const float*)d_in[3];
    const float* alpha_mean    = (const float*)d_in[4];
    const float* alpha_log_var = (const float*)d_in[5];
    const float* beta_base     = (const float*)d_in[6];
    const float* beta_offsets  = (const float*)d_in[7];
    const float* th0           = (const float*)d_in[8];
    const float* lv0           = (const float*)d_in[9];
    const float* q2k_w         = (const float*)d_in[10];
    const float* q2k_b         = (const float*)d_in[11];
    const float* qa_w          = (const float*)d_in[12];
    const float* qa_b          = (const float*)d_in[13];
    const float* qae_w         = (const float*)d_in[14];
    const float* qae_b         = (const float*)d_in[15];
    const float* pred_w        = (const float*)d_in[16];
    const float* pred_bs       = (const float*)d_in[17];
    const float* alpha_noise   = (const float*)d_in[18];
    const float* beta_noise    = (const float*)d_in[19];
    float* ws  = (float*)d_ws;
    float* out = (float*)d_out;

    k_prep<<<dim3(787), dim3(256), 0, stream>>>(
        q_ids, responses, q_table, key_embeds, q2k_w, q2k_b,
        alpha_mean, alpha_log_var, beta_base, beta_offsets,
        alpha_noise, beta_noise, qa_w, qa_b, qae_w, qae_b,
        pred_w, th0, lv0, ws);
    k_reduce<<<dim3(1024), dim3(512), 0, stream>>>(ws);
    k_scan<<<dim3(64), dim3(64), 0, stream>>>(ws);
    k_pred<<<dim3(1024), dim3(512), 0, stream>>>(q_ids, pred_bs, ws, out);
}